// Round 10
// baseline (279.836 us; speedup 1.0000x reference)
//
#include <hip/hip_runtime.h>
#include <hip/hip_cooperative_groups.h>
#include <math.h>

namespace cg = cooperative_groups;

#define NN 2048
#define BB 4
#define HD 128
#define CNUM 8
#define GB 256              // grid blocks (1 per CU, cooperative co-residency)
#define TB 512              // threads per block (8 waves)
#define NTH (GB * TB)       // 131072 threads
#define ZCNT ((BB * NN * (1 + 2 * HD)) / 4)   // float4 count of [dv|Z1|Z2]

typedef unsigned long long u64;

// EXACT branchless top-3 (R7/R9, passed absmax 0.0): key = (bits(sq)<<32)|j.
// sq >= 0 so float bits monotonic; u64 order == exact (sq,j) lexicographic ==
// reference tie-break. (11-bit-truncated u32 key FAILED in R8: 1.4e-3.)
__device__ __forceinline__ u64 pack_key(float sq, int j) {
    return ((u64)__float_as_uint(sq) << 32) | (unsigned)j;
}
__device__ __forceinline__ void ins3(u64 k, u64& k0, u64& k1, u64& k2) {
    u64 a = k  < k2 ? k  : k2;
    u64 b = k0 > a  ? k0 : a;
    k0    = k0 < a  ? k0 : a;
    k2    = k1 > b  ? k1 : b;
    k1    = k1 < b  ? k1 : b;
}

// Single cooperative kernel: phases separated by grid.sync(). Replaces the
// 7-10 dispatch pipeline (R1-R9) whose ~10-15us/dispatch overhead dominated
// (no single kernel ever exceeded 42us while totals were 119-146us).
__global__ __launch_bounds__(TB, 2) void k_fused(
        const float* __restrict__ x, const float* __restrict__ W1,
        const float* __restrict__ b1, const float* __restrict__ Wc,
        const float* __restrict__ bc, float* __restrict__ out,
        float4* __restrict__ pts, int* __restrict__ idx,
        float* __restrict__ vals, float* __restrict__ de,
        float* __restrict__ dv, float* __restrict__ Z1,
        float* __restrict__ Z2, float* __restrict__ pmax) {
    cg::grid_group grid = cg::this_grid();
    const int tid = threadIdx.x;
    const int gtid = blockIdx.x * TB + tid;

    // ---- phase 0: zero [dv|Z1|Z2] (contiguous, 8.4 MB) + pack pts ----
    {
        float4* z4 = (float4*)dv;
        const float4 z = make_float4(0.f, 0.f, 0.f, 0.f);
        for (int i = gtid; i < ZCNT; i += NTH) z4[i] = z;
        if (gtid < BB * NN) {
            const float a = x[3 * gtid], c = x[3 * gtid + 1], d = x[3 * gtid + 2];
            pts[gtid] = make_float4(a, c, d, a * a + c * c + d * d);
        }
    }
    grid.sync();

    // ---- phase 1: dist/top-3/incidence. 2048 waves x 4 centers ----
    {
        const int wv = gtid >> 6, lane = gtid & 63;
        for (int rep = 0; rep < 4; ++rep) {
            const int c = wv * 4 + rep;             // [0, B*NN)
            const int b = c >> 11, i = c & (NN - 1);
            const float4* pb = pts + b * NN;
            const float4 ci = pb[i];
            u64 k0 = ~0ull, k1 = ~0ull, k2 = ~0ull;
            float dsA = 0.f, dsB = 0.f;
            for (int t = lane; t < NN; t += 256) {  // 8 iters, 4 indep chains
                const float4 pa = pb[t];
                const float4 pv = pb[t + 64];
                const float4 pc = pb[t + 128];
                const float4 pd = pb[t + 192];
                const float qa = fmaxf(ci.w + pa.w - 2.0f * (ci.x * pa.x + ci.y * pa.y + ci.z * pa.z), 0.0f);
                const float qb = fmaxf(ci.w + pv.w - 2.0f * (ci.x * pv.x + ci.y * pv.y + ci.z * pv.z), 0.0f);
                const float qc = fmaxf(ci.w + pc.w - 2.0f * (ci.x * pc.x + ci.y * pc.y + ci.z * pc.z), 0.0f);
                const float qd = fmaxf(ci.w + pd.w - 2.0f * (ci.x * pd.x + ci.y * pd.y + ci.z * pd.z), 0.0f);
                dsA += __builtin_amdgcn_sqrtf(qa + 1e-12f) + __builtin_amdgcn_sqrtf(qc + 1e-12f);
                dsB += __builtin_amdgcn_sqrtf(qb + 1e-12f) + __builtin_amdgcn_sqrtf(qd + 1e-12f);
                ins3(pack_key(qa, t),       k0, k1, k2);
                ins3(pack_key(qb, t + 64),  k0, k1, k2);
                ins3(pack_key(qc, t + 128), k0, k1, k2);
                ins3(pack_key(qd, t + 192), k0, k1, k2);
            }
            float dsum = dsA + dsB;
            for (int off = 32; off > 0; off >>= 1) {
                const u64 o0 = __shfl_xor(k0, off);
                const u64 o1 = __shfl_xor(k1, off);
                const u64 o2 = __shfl_xor(k2, off);
                dsum += __shfl_xor(dsum, off);
                ins3(o0, k0, k1, k2);
                ins3(o1, k0, k1, k2);
                ins3(o2, k0, k1, k2);
            }
            if (lane == 0) {
                const float s0 = __uint_as_float((unsigned)(k0 >> 32));
                const float s1 = __uint_as_float((unsigned)(k1 >> 32));
                const float s2 = __uint_as_float((unsigned)(k2 >> 32));
                const int   i0 = (int)(k0 & 0xffffffffu);
                const int   i1 = (int)(k1 & 0xffffffffu);
                const int   i2 = (int)(k2 & 0xffffffffu);
                const float avg = dsum * (1.0f / NN);
                const float inva2 = 1.0f / (avg * avg);
                const float v0 = expf(-s0 * inva2);
                const float v1 = expf(-s1 * inva2);
                const float v2 = expf(-s2 * inva2);
                const int base = c * 3;
                idx[base] = i0; idx[base + 1] = i1; idx[base + 2] = i2;
                vals[base] = v0; vals[base + 1] = v1; vals[base + 2] = v2;
                de[c] = v0 + v1 + v2;
                atomicAdd(&dv[b * NN + i0], v0);
                atomicAdd(&dv[b * NN + i1], v1);
                atomicAdd(&dv[b * NN + i2], v2);
            }
        }
    }
    grid.sync();

    // ---- phase 2: conv1 scatter: Z1 += H^T-weighted W1 rows ----
    for (int pass = 0; pass < 8; ++pass) {
        const int gi = pass * NTH + gtid;           // [0, B*NN*HD)
        const int ge = gi >> 7;                     // global edge [0, B*NN)
        const int h = gi & (HD - 1);
        const int b = ge >> 11;
        const int base = ge * 3;
        const int j0 = idx[base], j1 = idx[base + 1], j2 = idx[base + 2];
        const float v0 = vals[base], v1 = vals[base + 1], v2 = vals[base + 2];
        const float ide = 1.0f / de[ge];
        const float g0 = v0 * rsqrtf(dv[b * NN + j0]);
        const float g1 = v1 * rsqrtf(dv[b * NN + j1]);
        const float g2 = v2 * rsqrtf(dv[b * NN + j2]);
        const float y = ide * (g0 * W1[j0 * HD + h] + g1 * W1[j1 * HD + h] + g2 * W1[j2 * HD + h]);
        atomicAdd(&Z1[((size_t)(b * NN + j0)) * HD + h], v0 * y);
        atomicAdd(&Z1[((size_t)(b * NN + j1)) * HD + h], v1 * y);
        atomicAdd(&Z1[((size_t)(b * NN + j2)) * HD + h], v2 * y);
    }
    grid.sync();

    // ---- phase 3: conv2 scatter on f1 = dv2*Z1 + b1 ----
    for (int pass = 0; pass < 8; ++pass) {
        const int gi = pass * NTH + gtid;
        const int ge = gi >> 7;
        const int h = gi & (HD - 1);
        const int b = ge >> 11;
        const int base = ge * 3;
        const int j0 = idx[base], j1 = idx[base + 1], j2 = idx[base + 2];
        const float v0 = vals[base], v1 = vals[base + 1], v2 = vals[base + 2];
        const float ide = 1.0f / de[ge];
        const float bh = b1[h];
        const float d0 = rsqrtf(dv[b * NN + j0]);
        const float d1 = rsqrtf(dv[b * NN + j1]);
        const float d2 = rsqrtf(dv[b * NN + j2]);
        const float f0 = d0 * Z1[((size_t)(b * NN + j0)) * HD + h] + bh;
        const float f1 = d1 * Z1[((size_t)(b * NN + j1)) * HD + h] + bh;
        const float f2 = d2 * Z1[((size_t)(b * NN + j2)) * HD + h] + bh;
        const float y = ide * (v0 * d0 * f0 + v1 * d1 * f1 + v2 * d2 * f2);
        atomicAdd(&Z2[((size_t)(b * NN + j0)) * HD + h], v0 * y);
        atomicAdd(&Z2[((size_t)(b * NN + j1)) * HD + h], v1 * y);
        atomicAdd(&Z2[((size_t)(b * NN + j2)) * HD + h], v2 * y);
    }
    grid.sync();

    // ---- phase 4: partial max over 32-node chunks (1 block per (b,chunk)) ----
    __shared__ float sm[4][HD];
    {
        const int b = blockIdx.x >> 6, ch = blockIdx.x & 63;
        const int h = tid & (HD - 1), sub = tid >> 7;   // 4 sub-chunks x 8 nodes
        float mx = -INFINITY;
        for (int n = 0; n < 8; ++n) {
            const int g = b * NN + ch * 32 + sub * 8 + n;
            mx = fmaxf(mx, rsqrtf(dv[g]) * Z2[(size_t)g * HD + h]);
        }
        sm[sub][h] = mx;
        __syncthreads();
        if (sub == 0)
            pmax[(b * 64 + ch) * HD + h] =
                fmaxf(fmaxf(sm[0][h], sm[1][h]), fmaxf(sm[2][h], sm[3][h]));
    }
    grid.sync();

    // ---- phase 5: merge 64 chunk-maxes + classifier (blocks 0..3) ----
    if (blockIdx.x < BB) {
        const int b = blockIdx.x;
        __shared__ float smax[HD];
        if (tid < HD) {
            float mx = -INFINITY;
            for (int c = 0; c < 64; ++c)
                mx = fmaxf(mx, pmax[(b * 64 + c) * HD + tid]);
            smax[tid] = mx;
        }
        __syncthreads();
        if (tid < CNUM) {
            float acc = bc[tid];
            for (int q = 0; q < HD; ++q) acc += smax[q] * Wc[q * CNUM + tid];
            out[b * CNUM + tid] = acc;
        }
    }
}

extern "C" void kernel_launch(void* const* d_in, const int* in_sizes, int n_in,
                              void* d_out, int out_size, void* d_ws, size_t ws_size,
                              hipStream_t stream) {
    const float* x  = (const float*)d_in[0];   // [B,N,3]
    const float* W1 = (const float*)d_in[1];   // [N,H1]
    const float* b1 = (const float*)d_in[2];   // [H1]
    const float* Wc = (const float*)d_in[3];   // [H1,C]
    const float* bc = (const float*)d_in[4];   // [C]
    float* out = (float*)d_out;                // [B,C]

    float* ws = (float*)d_ws;
    float*  dv   = ws;                                  // B*N      (zeroed in-kernel)
    float*  Z1   = dv + BB * NN;                        // B*N*HD   (zeroed in-kernel)
    float*  Z2   = Z1 + (size_t)BB * NN * HD;           // B*N*HD   (zeroed in-kernel)
    float*  vals = Z2 + (size_t)BB * NN * HD;           // B*N*3
    float*  de   = vals + BB * NN * 3;                  // B*N
    int*    idx  = (int*)(de + BB * NN);                // B*N*3
    float*  pmax = (float*)(idx + BB * NN * 3);         // B*64*HD
    float4* pts  = (float4*)(pmax + BB * 64 * HD);      // B*N float4 (16B-aligned)

    void* args[] = { (void*)&x, (void*)&W1, (void*)&b1, (void*)&Wc, (void*)&bc,
                     (void*)&out, (void*)&pts, (void*)&idx, (void*)&vals,
                     (void*)&de, (void*)&dv, (void*)&Z1, (void*)&Z2, (void*)&pmax };
    hipLaunchCooperativeKernel((void*)k_fused, dim3(GB), dim3(TB), args, 0, stream);
}

// Round 11
// 134.442 us; speedup vs baseline: 2.0815x; 2.0815x over previous
//
#include <hip/hip_runtime.h>
#include <math.h>

#define NN 2048
#define BB 4
#define HD 128
#define CNUM 8
#define WPB 4               // waves (= centers) per block in k_dist
#define ZF4 ((BB * NN * (1 + 2 * HD)) / 4)   // float4 count of [dv|Z1|Z2]

typedef unsigned long long u64;

// EXACT branchless top-3 (verified absmax 0.0 in R7/R9): key = (bits(sq)<<32)|j.
// sq >= 0 so float bits monotonic; u64 order == exact (sq,j) lexicographic ==
// reference tie-break. (11-bit-truncated u32 key FAILED in R8 at 1.4e-3.)
__device__ __forceinline__ u64 pack_key(float sq, int j) {
    return ((u64)__float_as_uint(sq) << 32) | (unsigned)j;
}
__device__ __forceinline__ void ins3(u64 k, u64& k0, u64& k1, u64& k2) {
    u64 a = k  < k2 ? k  : k2;
    u64 b = k0 > a  ? k0 : a;
    k0    = k0 < a  ? k0 : a;
    k2    = k1 > b  ? k1 : b;
    k1    = k1 < b  ? k1 : b;
}

// K0: zero [dv|Z1|Z2] (8.4 MB, float4 stores) + pack pts. Replaces
// hipMemsetAsync + k_prep (one dispatch instead of two).
__global__ __launch_bounds__(256) void k_init(const float* __restrict__ x,
                                              float* __restrict__ zbase,
                                              float4* __restrict__ pts) {
    const int gtid = blockIdx.x * 256 + threadIdx.x;   // 65536 threads
    float4* z4 = (float4*)zbase;
    const float4 z = make_float4(0.f, 0.f, 0.f, 0.f);
    for (int i = gtid; i < ZF4; i += 65536) z4[i] = z;
    if (gtid < BB * NN) {
        const float a = x[3 * gtid], c = x[3 * gtid + 1], d = x[3 * gtid + 2];
        pts[gtid] = make_float4(a, c, d, a * a + c * c + d * d);
    }
}

// K1: one wave per center, coalesced global loads with REGISTER PREFETCH
// (load iter t+256 before computing iter t -- R7 stalled on L2 latency),
// exact-key branchless top-3, raw v_sqrt_f32, butterfly merge, fused epilogue.
__global__ __launch_bounds__(256) void k_dist(
        const float4* __restrict__ pts,
        int* __restrict__ idx, float* __restrict__ vals,
        float* __restrict__ de, float* __restrict__ dv) {
    const int b = blockIdx.y;
    const float4* pb = pts + b * NN;
    const int wave = threadIdx.x >> 6;
    const int lane = threadIdx.x & 63;
    const int i = blockIdx.x * WPB + wave;          // this wave's center
    const float4 ci = pb[i];                        // wave-uniform -> broadcast
    u64 k0 = ~0ull, k1 = ~0ull, k2 = ~0ull;
    float dsA = 0.f, dsB = 0.f;
    float4 pa = pb[lane], pv = pb[lane + 64], pc = pb[lane + 128], pd = pb[lane + 192];
    for (int t = lane; t < NN; t += 256) {          // 8 iters, 4 indep chains
        const float4 ca = pa, cv = pv, cc = pc, cd = pd;
        if (t + 256 < NN) {                         // prefetch next iteration
            pa = pb[t + 256];
            pv = pb[t + 320];
            pc = pb[t + 384];
            pd = pb[t + 448];
        }
        const float qa = fmaxf(ci.w + ca.w - 2.0f * (ci.x * ca.x + ci.y * ca.y + ci.z * ca.z), 0.0f);
        const float qb = fmaxf(ci.w + cv.w - 2.0f * (ci.x * cv.x + ci.y * cv.y + ci.z * cv.z), 0.0f);
        const float qc = fmaxf(ci.w + cc.w - 2.0f * (ci.x * cc.x + ci.y * cc.y + ci.z * cc.z), 0.0f);
        const float qd = fmaxf(ci.w + cd.w - 2.0f * (ci.x * cd.x + ci.y * cd.y + ci.z * cd.z), 0.0f);
        dsA += __builtin_amdgcn_sqrtf(qa + 1e-12f) + __builtin_amdgcn_sqrtf(qc + 1e-12f);
        dsB += __builtin_amdgcn_sqrtf(qb + 1e-12f) + __builtin_amdgcn_sqrtf(qd + 1e-12f);
        ins3(pack_key(qa, t),       k0, k1, k2);
        ins3(pack_key(qb, t + 64),  k0, k1, k2);
        ins3(pack_key(qc, t + 128), k0, k1, k2);
        ins3(pack_key(qd, t + 192), k0, k1, k2);
    }
    float dsum = dsA + dsB;
    // butterfly merge: keys unique (j embedded) -> plain u64 merge
    for (int off = 32; off > 0; off >>= 1) {
        const u64 o0 = __shfl_xor(k0, off);
        const u64 o1 = __shfl_xor(k1, off);
        const u64 o2 = __shfl_xor(k2, off);
        dsum += __shfl_xor(dsum, off);
        ins3(o0, k0, k1, k2);
        ins3(o1, k0, k1, k2);
        ins3(o2, k0, k1, k2);
    }
    if (lane == 0) {
        const float s0 = __uint_as_float((unsigned)(k0 >> 32));
        const float s1 = __uint_as_float((unsigned)(k1 >> 32));
        const float s2 = __uint_as_float((unsigned)(k2 >> 32));
        const int   i0 = (int)(k0 & 0xffffffffu);
        const int   i1 = (int)(k1 & 0xffffffffu);
        const int   i2 = (int)(k2 & 0xffffffffu);
        const float avg = dsum * (1.0f / NN);
        const float inva2 = 1.0f / (avg * avg);
        const float v0 = expf(-s0 * inva2);
        const float v1 = expf(-s1 * inva2);
        const float v2 = expf(-s2 * inva2);
        const int base = (b * NN + i) * 3;
        idx[base] = i0; idx[base + 1] = i1; idx[base + 2] = i2;
        vals[base] = v0; vals[base + 1] = v1; vals[base + 2] = v2;
        de[b * NN + i] = v0 + v1 + v2;
        atomicAdd(&dv[b * NN + i0], v0);
        atomicAdd(&dv[b * NN + i1], v1);
        atomicAdd(&dv[b * NN + i2], v2);
    }
}

// K2: first G-application on W1. 256-thread blocks, 2 edges per block.
__global__ void k_conv1(const float* __restrict__ W1, const int* __restrict__ idx,
                        const float* __restrict__ vals, const float* __restrict__ de,
                        const float* __restrict__ dv, float* __restrict__ Z1) {
    const int e = blockIdx.x * 2 + (threadIdx.x >> 7);
    const int b = blockIdx.y, h = threadIdx.x & (HD - 1);
    const int base = (b * NN + e) * 3;
    const int j0 = idx[base], j1 = idx[base + 1], j2 = idx[base + 2];
    const float v0 = vals[base], v1 = vals[base + 1], v2 = vals[base + 2];
    const float ide = 1.0f / de[b * NN + e];
    const float g0 = v0 * rsqrtf(dv[b * NN + j0]);
    const float g1 = v1 * rsqrtf(dv[b * NN + j1]);
    const float g2 = v2 * rsqrtf(dv[b * NN + j2]);
    const float y = ide * (g0 * W1[j0 * HD + h] + g1 * W1[j1 * HD + h] + g2 * W1[j2 * HD + h]);
    atomicAdd(&Z1[((size_t)(b * NN + j0)) * HD + h], v0 * y);
    atomicAdd(&Z1[((size_t)(b * NN + j1)) * HD + h], v1 * y);
    atomicAdd(&Z1[((size_t)(b * NN + j2)) * HD + h], v2 * y);
}

// K3: second G-application on f1 = dv2*Z1 + b1.
__global__ void k_conv2(const float* __restrict__ b1, const int* __restrict__ idx,
                        const float* __restrict__ vals, const float* __restrict__ de,
                        const float* __restrict__ dv, const float* __restrict__ Z1,
                        float* __restrict__ Z2) {
    const int e = blockIdx.x * 2 + (threadIdx.x >> 7);
    const int b = blockIdx.y, h = threadIdx.x & (HD - 1);
    const int base = (b * NN + e) * 3;
    const int j0 = idx[base], j1 = idx[base + 1], j2 = idx[base + 2];
    const float v0 = vals[base], v1 = vals[base + 1], v2 = vals[base + 2];
    const float ide = 1.0f / de[b * NN + e];
    const float bh = b1[h];
    const float d0 = rsqrtf(dv[b * NN + j0]);
    const float d1 = rsqrtf(dv[b * NN + j1]);
    const float d2 = rsqrtf(dv[b * NN + j2]);
    const float f0 = d0 * Z1[((size_t)(b * NN + j0)) * HD + h] + bh;
    const float f1 = d1 * Z1[((size_t)(b * NN + j1)) * HD + h] + bh;
    const float f2 = d2 * Z1[((size_t)(b * NN + j2)) * HD + h] + bh;
    const float y = ide * (v0 * d0 * f0 + v1 * d1 * f1 + v2 * d2 * f2);
    atomicAdd(&Z2[((size_t)(b * NN + j0)) * HD + h], v0 * y);
    atomicAdd(&Z2[((size_t)(b * NN + j1)) * HD + h], v1 * y);
    atomicAdd(&Z2[((size_t)(b * NN + j2)) * HD + h], v2 * y);
}

// K4: full pool + classifier, one block per batch (1024 thr = 16 waves).
// Each eighth q scans 256 nodes for its h column; LDS reduce 8->1; classify.
// Replaces pool1+pool2 (one dispatch instead of two).
__global__ __launch_bounds__(1024) void k_pool(
        const float* __restrict__ Wc, const float* __restrict__ bc,
        const float* __restrict__ dv, const float* __restrict__ Z2,
        float* __restrict__ out) {
    __shared__ float sm[8][HD];
    __shared__ float smax[HD];
    const int b = blockIdx.x;
    const int h = threadIdx.x & (HD - 1);
    const int q = threadIdx.x >> 7;                 // 0..7
    float mx = -INFINITY;
    for (int n = 0; n < NN / 8; ++n) {
        const int g = b * NN + q * (NN / 8) + n;
        mx = fmaxf(mx, rsqrtf(dv[g]) * Z2[(size_t)g * HD + h]);
    }
    sm[q][h] = mx;
    __syncthreads();
    if (threadIdx.x < HD) {
        float m = sm[0][h];
        for (int p = 1; p < 8; ++p) m = fmaxf(m, sm[p][h]);
        smax[h] = m;
    }
    __syncthreads();
    if (threadIdx.x < CNUM) {
        float acc = bc[threadIdx.x];
        for (int k = 0; k < HD; ++k) acc += smax[k] * Wc[k * CNUM + threadIdx.x];
        out[b * CNUM + threadIdx.x] = acc;
    }
}

extern "C" void kernel_launch(void* const* d_in, const int* in_sizes, int n_in,
                              void* d_out, int out_size, void* d_ws, size_t ws_size,
                              hipStream_t stream) {
    const float* x  = (const float*)d_in[0];   // [B,N,3]
    const float* W1 = (const float*)d_in[1];   // [N,H1]
    const float* b1 = (const float*)d_in[2];   // [H1]
    const float* Wc = (const float*)d_in[3];   // [H1,C]
    const float* bc = (const float*)d_in[4];   // [C]
    float* out = (float*)d_out;                // [B,C]

    float* ws = (float*)d_ws;
    float*  dv   = ws;                                  // B*N      (zeroed by k_init)
    float*  Z1   = dv + BB * NN;                        // B*N*HD   (zeroed by k_init)
    float*  Z2   = Z1 + (size_t)BB * NN * HD;           // B*N*HD   (zeroed by k_init)
    float*  vals = Z2 + (size_t)BB * NN * HD;           // B*N*3
    float*  de   = vals + BB * NN * 3;                  // B*N
    int*    idx  = (int*)(de + BB * NN);                // B*N*3
    float4* pts  = (float4*)(idx + BB * NN * 3);        // B*N float4 (16B-aligned)

    k_init<<<256, 256, 0, stream>>>(x, dv, pts);
    k_dist<<<dim3(NN / WPB, BB), 256, 0, stream>>>(pts, idx, vals, de, dv);
    k_conv1<<<dim3(NN / 2, BB), 256, 0, stream>>>(W1, idx, vals, de, dv, Z1);
    k_conv2<<<dim3(NN / 2, BB), 256, 0, stream>>>(b1, idx, vals, de, dv, Z1, Z2);
    k_pool<<<BB, 1024, 0, stream>>>(Wc, bc, dv, Z2, out);
}

// Round 12
// 127.774 us; speedup vs baseline: 2.1901x; 1.0522x over previous
//
#include <hip/hip_runtime.h>
#include <math.h>

#define NN 2048
#define BB 4
#define HD 128
#define CNUM 8
#define WPB 4               // waves (= centers) per block in k_dist
#define PCHUNK 32           // nodes per block in k_pool1
#define NCHUNKS (NN / PCHUNK)   // 64
#define ZF4 ((BB * NN * (1 + 2 * HD)) / 4)   // float4 count of [dv|Z1|Z2]

typedef unsigned long long u64;

// EXACT branchless top-3 (verified absmax 0.0 in R7/R9): key = (bits(sq)<<32)|j.
// sq >= 0 so float bits monotonic; u64 order == exact (sq,j) lexicographic ==
// reference tie-break. (11-bit-truncated u32 key FAILED in R8 at 1.4e-3.)
__device__ __forceinline__ u64 pack_key(float sq, int j) {
    return ((u64)__float_as_uint(sq) << 32) | (unsigned)j;
}
__device__ __forceinline__ void ins3(u64 k, u64& k0, u64& k1, u64& k2) {
    u64 a = k  < k2 ? k  : k2;
    u64 b = k0 > a  ? k0 : a;
    k0    = k0 < a  ? k0 : a;
    k2    = k1 > b  ? k1 : b;
    k1    = k1 < b  ? k1 : b;
}

// K0: zero [dv|Z1|Z2] (8.4 MB, float4 stores) + pack pts.
__global__ __launch_bounds__(256) void k_init(const float* __restrict__ x,
                                              float* __restrict__ zbase,
                                              float4* __restrict__ pts) {
    const int gtid = blockIdx.x * 256 + threadIdx.x;   // 65536 threads
    float4* z4 = (float4*)zbase;
    const float4 z = make_float4(0.f, 0.f, 0.f, 0.f);
    for (int i = gtid; i < ZF4; i += 65536) z4[i] = z;
    if (gtid < BB * NN) {
        const float a = x[3 * gtid], c = x[3 * gtid + 1], d = x[3 * gtid + 2];
        pts[gtid] = make_float4(a, c, d, a * a + c * c + d * d);
    }
}

// K1: one wave per center, coalesced global loads with register prefetch,
// exact-key branchless top-3, raw v_sqrt_f32, butterfly merge, fused epilogue.
__global__ __launch_bounds__(256) void k_dist(
        const float4* __restrict__ pts,
        int* __restrict__ idx, float* __restrict__ vals,
        float* __restrict__ de, float* __restrict__ dv) {
    const int b = blockIdx.y;
    const float4* pb = pts + b * NN;
    const int wave = threadIdx.x >> 6;
    const int lane = threadIdx.x & 63;
    const int i = blockIdx.x * WPB + wave;          // this wave's center
    const float4 ci = pb[i];                        // wave-uniform -> broadcast
    u64 k0 = ~0ull, k1 = ~0ull, k2 = ~0ull;
    float dsA = 0.f, dsB = 0.f;
    float4 pa = pb[lane], pv = pb[lane + 64], pc = pb[lane + 128], pd = pb[lane + 192];
    for (int t = lane; t < NN; t += 256) {          // 8 iters, 4 indep chains
        const float4 ca = pa, cv = pv, cc = pc, cd = pd;
        if (t + 256 < NN) {                         // prefetch next iteration
            pa = pb[t + 256];
            pv = pb[t + 320];
            pc = pb[t + 384];
            pd = pb[t + 448];
        }
        const float qa = fmaxf(ci.w + ca.w - 2.0f * (ci.x * ca.x + ci.y * ca.y + ci.z * ca.z), 0.0f);
        const float qb = fmaxf(ci.w + cv.w - 2.0f * (ci.x * cv.x + ci.y * cv.y + ci.z * cv.z), 0.0f);
        const float qc = fmaxf(ci.w + cc.w - 2.0f * (ci.x * cc.x + ci.y * cc.y + ci.z * cc.z), 0.0f);
        const float qd = fmaxf(ci.w + cd.w - 2.0f * (ci.x * cd.x + ci.y * cd.y + ci.z * cd.z), 0.0f);
        dsA += __builtin_amdgcn_sqrtf(qa + 1e-12f) + __builtin_amdgcn_sqrtf(qc + 1e-12f);
        dsB += __builtin_amdgcn_sqrtf(qb + 1e-12f) + __builtin_amdgcn_sqrtf(qd + 1e-12f);
        ins3(pack_key(qa, t),       k0, k1, k2);
        ins3(pack_key(qb, t + 64),  k0, k1, k2);
        ins3(pack_key(qc, t + 128), k0, k1, k2);
        ins3(pack_key(qd, t + 192), k0, k1, k2);
    }
    float dsum = dsA + dsB;
    // butterfly merge: keys unique (j embedded) -> plain u64 merge
    for (int off = 32; off > 0; off >>= 1) {
        const u64 o0 = __shfl_xor(k0, off);
        const u64 o1 = __shfl_xor(k1, off);
        const u64 o2 = __shfl_xor(k2, off);
        dsum += __shfl_xor(dsum, off);
        ins3(o0, k0, k1, k2);
        ins3(o1, k0, k1, k2);
        ins3(o2, k0, k1, k2);
    }
    if (lane == 0) {
        const float s0 = __uint_as_float((unsigned)(k0 >> 32));
        const float s1 = __uint_as_float((unsigned)(k1 >> 32));
        const float s2 = __uint_as_float((unsigned)(k2 >> 32));
        const int   i0 = (int)(k0 & 0xffffffffu);
        const int   i1 = (int)(k1 & 0xffffffffu);
        const int   i2 = (int)(k2 & 0xffffffffu);
        const float avg = dsum * (1.0f / NN);
        const float inva2 = 1.0f / (avg * avg);
        const float v0 = expf(-s0 * inva2);
        const float v1 = expf(-s1 * inva2);
        const float v2 = expf(-s2 * inva2);
        const int base = (b * NN + i) * 3;
        idx[base] = i0; idx[base + 1] = i1; idx[base + 2] = i2;
        vals[base] = v0; vals[base + 1] = v1; vals[base + 2] = v2;
        de[b * NN + i] = v0 + v1 + v2;
        atomicAdd(&dv[b * NN + i0], v0);
        atomicAdd(&dv[b * NN + i1], v1);
        atomicAdd(&dv[b * NN + i2], v2);
    }
}

// K2: first G-application on W1. 256-thread blocks, 2 edges per block.
__global__ void k_conv1(const float* __restrict__ W1, const int* __restrict__ idx,
                        const float* __restrict__ vals, const float* __restrict__ de,
                        const float* __restrict__ dv, float* __restrict__ Z1) {
    const int e = blockIdx.x * 2 + (threadIdx.x >> 7);
    const int b = blockIdx.y, h = threadIdx.x & (HD - 1);
    const int base = (b * NN + e) * 3;
    const int j0 = idx[base], j1 = idx[base + 1], j2 = idx[base + 2];
    const float v0 = vals[base], v1 = vals[base + 1], v2 = vals[base + 2];
    const float ide = 1.0f / de[b * NN + e];
    const float g0 = v0 * rsqrtf(dv[b * NN + j0]);
    const float g1 = v1 * rsqrtf(dv[b * NN + j1]);
    const float g2 = v2 * rsqrtf(dv[b * NN + j2]);
    const float y = ide * (g0 * W1[j0 * HD + h] + g1 * W1[j1 * HD + h] + g2 * W1[j2 * HD + h]);
    atomicAdd(&Z1[((size_t)(b * NN + j0)) * HD + h], v0 * y);
    atomicAdd(&Z1[((size_t)(b * NN + j1)) * HD + h], v1 * y);
    atomicAdd(&Z1[((size_t)(b * NN + j2)) * HD + h], v2 * y);
}

// K3: second G-application on f1 = dv2*Z1 + b1.
__global__ void k_conv2(const float* __restrict__ b1, const int* __restrict__ idx,
                        const float* __restrict__ vals, const float* __restrict__ de,
                        const float* __restrict__ dv, const float* __restrict__ Z1,
                        float* __restrict__ Z2) {
    const int e = blockIdx.x * 2 + (threadIdx.x >> 7);
    const int b = blockIdx.y, h = threadIdx.x & (HD - 1);
    const int base = (b * NN + e) * 3;
    const int j0 = idx[base], j1 = idx[base + 1], j2 = idx[base + 2];
    const float v0 = vals[base], v1 = vals[base + 1], v2 = vals[base + 2];
    const float ide = 1.0f / de[b * NN + e];
    const float bh = b1[h];
    const float d0 = rsqrtf(dv[b * NN + j0]);
    const float d1 = rsqrtf(dv[b * NN + j1]);
    const float d2 = rsqrtf(dv[b * NN + j2]);
    const float f0 = d0 * Z1[((size_t)(b * NN + j0)) * HD + h] + bh;
    const float f1 = d1 * Z1[((size_t)(b * NN + j1)) * HD + h] + bh;
    const float f2 = d2 * Z1[((size_t)(b * NN + j2)) * HD + h] + bh;
    const float y = ide * (v0 * d0 * f0 + v1 * d1 * f1 + v2 * d2 * f2);
    atomicAdd(&Z2[((size_t)(b * NN + j0)) * HD + h], v0 * y);
    atomicAdd(&Z2[((size_t)(b * NN + j1)) * HD + h], v1 * y);
    atomicAdd(&Z2[((size_t)(b * NN + j2)) * HD + h], v2 * y);
}

// K4a: partial max over 32-node chunks. grid (B, 64) x 128 threads (256 blocks
// -- R11's 4-block merged pool was the regression, same failure mode as R2).
__global__ void k_pool1(const float* __restrict__ dv, const float* __restrict__ Z2,
                        float* __restrict__ pmax) {
    const int b = blockIdx.x, ch = blockIdx.y, h = threadIdx.x;
    const int v0 = ch * PCHUNK;
    float mx = -INFINITY;
    for (int v = v0; v < v0 + PCHUNK; ++v) {
        const float d2 = rsqrtf(dv[b * NN + v]);
        mx = fmaxf(mx, d2 * Z2[((size_t)(b * NN + v)) * HD + h]);
    }
    pmax[(b * NCHUNKS + ch) * HD + h] = mx;
}

// K4b: merge partial maxes + classifier. grid B x 128 threads.
__global__ void k_pool2(const float* __restrict__ Wc, const float* __restrict__ bc,
                        const float* __restrict__ pmax, float* __restrict__ out) {
    __shared__ float smax[HD];
    const int b = blockIdx.x, h = threadIdx.x;
    float mx = -INFINITY;
    for (int c = 0; c < NCHUNKS; ++c)
        mx = fmaxf(mx, pmax[(b * NCHUNKS + c) * HD + h]);
    smax[h] = mx;
    __syncthreads();
    if (h < CNUM) {
        float acc = bc[h];
        for (int q = 0; q < HD; ++q) acc += smax[q] * Wc[q * CNUM + h];
        out[b * CNUM + h] = acc;
    }
}

extern "C" void kernel_launch(void* const* d_in, const int* in_sizes, int n_in,
                              void* d_out, int out_size, void* d_ws, size_t ws_size,
                              hipStream_t stream) {
    const float* x  = (const float*)d_in[0];   // [B,N,3]
    const float* W1 = (const float*)d_in[1];   // [N,H1]
    const float* b1 = (const float*)d_in[2];   // [H1]
    const float* Wc = (const float*)d_in[3];   // [H1,C]
    const float* bc = (const float*)d_in[4];   // [C]
    float* out = (float*)d_out;                // [B,C]

    float* ws = (float*)d_ws;
    float*  dv   = ws;                                  // B*N      (zeroed by k_init)
    float*  Z1   = dv + BB * NN;                        // B*N*HD   (zeroed by k_init)
    float*  Z2   = Z1 + (size_t)BB * NN * HD;           // B*N*HD   (zeroed by k_init)
    float*  vals = Z2 + (size_t)BB * NN * HD;           // B*N*3
    float*  de   = vals + BB * NN * 3;                  // B*N
    int*    idx  = (int*)(de + BB * NN);                // B*N*3
    float4* pts  = (float4*)(idx + BB * NN * 3);        // B*N float4 (16B-aligned)
    float*  pmax = (float*)(pts + BB * NN);             // B*64*HD

    k_init<<<256, 256, 0, stream>>>(x, dv, pts);
    k_dist<<<dim3(NN / WPB, BB), 256, 0, stream>>>(pts, idx, vals, de, dv);
    k_conv1<<<dim3(NN / 2, BB), 256, 0, stream>>>(W1, idx, vals, de, dv, Z1);
    k_conv2<<<dim3(NN / 2, BB), 256, 0, stream>>>(b1, idx, vals, de, dv, Z1, Z2);
    k_pool1<<<dim3(BB, NCHUNKS), HD, 0, stream>>>(dv, Z2, pmax);
    k_pool2<<<BB, HD, 0, stream>>>(Wc, bc, pmax, out);
}